// Round 10
// baseline (214.959 us; speedup 1.0000x reference)
//
#include <hip/hip_runtime.h>

typedef unsigned short u16;
typedef unsigned int   u32;
typedef __attribute__((ext_vector_type(2))) float    f32x2;
typedef __attribute__((ext_vector_type(4))) float    f32x4;
typedef __attribute__((ext_vector_type(8))) __bf16   bf16x8;
typedef __attribute__((ext_vector_type(8))) unsigned short u16x8;
typedef __attribute__((ext_vector_type(4))) unsigned short u16x4;
typedef __attribute__((ext_vector_type(4))) float    float4v;

#define MFMA16(a,b,c) __builtin_amdgcn_mfma_f32_16x16x32_bf16((a),(b),(c),0,0,0)
// softmax scale folded with log2(e): 0.125 * 1.4426950408889634
#define QSCALE 0.18033688011112042f

__device__ __forceinline__ u16 f2b(float f){
  union { float f; unsigned u; } v; v.f = f;
  return (u16)((v.u + 0x7fffu + ((v.u >> 16) & 1u)) >> 16);
}

__device__ __forceinline__ u32 cvt_pk_bf16(float lo, float hi){
  u32 r;
  asm("v_cvt_pk_bf16_f32 %0, %1, %2" : "=v"(r) : "v"(lo), "v"(hi));
  return r;
}

__device__ __forceinline__ float exp2_raw(float x){
  float r;
  asm("v_exp_f32 %0, %1" : "=v"(r) : "v"(x));
  return r;
}

__device__ __forceinline__ f32x2 lo2(f32x4 v){ return __builtin_shufflevector(v, v, 0, 1); }
__device__ __forceinline__ f32x2 hi2(f32x4 v){ return __builtin_shufflevector(v, v, 2, 3); }

__device__ __forceinline__ void gload_lds16(const void* g, void* l){
  __builtin_amdgcn_global_load_lds(
      (const __attribute__((address_space(1))) void*)g,
      (__attribute__((address_space(3))) void*)l, 16, 0, 0);
}

// ---------------- cast fp32 -> bf16 (elementwise, vectorized) ----------------
__global__ void cast_f32_bf16(const float* __restrict__ in, u16* __restrict__ out, int n4){
  int i = blockIdx.x * blockDim.x + threadIdx.x;
  int st = gridDim.x * blockDim.x;
  for (; i < n4; i += st){
    float4v v = ((const float4v*)in)[i];
    u16x4 o;
    o[0] = f2b(v[0]); o[1] = f2b(v[1]); o[2] = f2b(v[2]); o[3] = f2b(v[3]);
    ((u16x4*)out)[i] = o;
  }
}

// ------------- transpose + cast: src fp32 [R][C] -> dst bf16 [C][R] ----------
__global__ void tcast(const float* __restrict__ src, u16* __restrict__ dst, int R, int C){
  __shared__ float tile[32][33];
  int tx = threadIdx.x, ty = threadIdx.y;
  int c0 = blockIdx.x * 32, r0 = blockIdx.y * 32;
  #pragma unroll
  for (int i = 0; i < 4; i++)
    tile[ty + i*8][tx] = src[(long)(r0 + ty + i*8) * C + c0 + tx];
  __syncthreads();
  #pragma unroll
  for (int i = 0; i < 4; i++)
    dst[(long)(c0 + ty + i*8) * R + r0 + tx] = f2b(tile[tx][ty + i*8]);
}

// ====== k-split GEMM: C = A[M,K] @ Bt[N,K]^T, BM=256 BN=128, BK=64 ===========
// (unchanged from R9: 3-slot ring, vmcnt(6)/tile, XOR swizzle, XCD remap)
template<int MODE>
__global__ __launch_bounds__(512, 2) void gemm8(
    const u16* __restrict__ A, const u16* __restrict__ Bt,
    int M, int N, int K,
    float* __restrict__ outF, const float* __restrict__ bias,
    u16* __restrict__ qb, u16* __restrict__ kb, u16* __restrict__ vtb)
{
  extern __shared__ u16 lds[];
  u16* aL = lds;             // 3 slots x 16384 u16 (32KB)
  u16* bL = lds + 49152;     // 3 slots x  8192 u16 (16KB)

  const int t  = threadIdx.x;          // 0..511
  const int l  = t & 63, lr = l & 15, lg = l >> 4;
  const int w  = t >> 6;               // 0..7
  const int wm = w >> 2, wn = (w >> 1) & 1, wk = w & 1;
  const int bid = blockIdx.x;
  const int xcd = bid & 7, idx = bid >> 3;
  const long mbase = (long)(xcd*4 + (idx & 3)) * 256;
  const long nbase = (long)(idx >> 2) * 128;

  const int xr0 = t >> 3;
  const int xc  = t & 7;
  const int xswz = (xc ^ (xr0 & 7)) << 3;

#define STG(F_) do { \
    const int T_ = (F_) >> 2, h_ = (F_) & 3, slot_ = T_ % 3; \
    if ((h_ & 1) == 0){ const int ah = h_ >> 1; \
      const u16* g_ = A + (mbase + ah*128 + xr0)*(long)K + T_*64 + xswz; \
      u16* d_ = aL + slot_*16384 + ah*8192 + t*8; \
      gload_lds16(g_, d_); \
      gload_lds16(g_ + 64*(long)K, d_ + 4096); \
    } else { const int bh_ = h_ >> 1; \
      const u16* g_ = Bt + (nbase + bh_*64 + xr0)*(long)K + T_*64 + xswz; \
      gload_lds16(g_, bL + slot_*8192 + bh_*4096 + t*8); } \
  } while(0)

#define VMCNT(n) asm volatile("s_waitcnt vmcnt(" #n ")" ::: "memory")
#define BAR() __builtin_amdgcn_s_barrier()

  f32x4 z = {0.f,0.f,0.f,0.f};
  f32x4 acc[8][4];
  #pragma unroll
  for (int a = 0; a < 8; a++)
    #pragma unroll
    for (int j = 0; j < 4; j++) acc[a][j] = z;

  const int kc = wk*4;   // k-half chunk base for this wave

  STG(0); STG(1); STG(2); STG(3);
  STG(4); STG(5); STG(6); STG(7);
  VMCNT(6);
  BAR();

  for (int T = 0; T < 16; ++T){
    const int abuf = (T % 3) * 16384;
    const int bbuf = (T % 3) * 8192;
    bf16x8 afi[8], bfj[4];

    #pragma unroll
    for (int j = 0; j < 4; j++){
      const int rb = wn*64 + j*16 + lr;
      bfj[j] = *(const bf16x8*)&bL[bbuf + rb*64 + (((kc+lg)^(rb&7))<<3)];
    }
    #pragma unroll
    for (int i = 0; i < 8; i++){
      const int ra = wm*128 + i*16 + lr;
      afi[i] = *(const bf16x8*)&aL[abuf + ra*64 + (((kc+lg)^(ra&7))<<3)];
    }
    if (T < 14){
      STG(4*(T+2)); STG(4*(T+2)+1); STG(4*(T+2)+2); STG(4*(T+2)+3);
      VMCNT(6);
    } else if (T == 14){
      VMCNT(0);
    }
    BAR();
    __builtin_amdgcn_s_setprio(1);
    #pragma unroll
    for (int i = 0; i < 8; i++)
      #pragma unroll
      for (int j = 0; j < 4; j++)
        acc[i][j] = MFMA16(afi[i], bfj[j], acc[i][j]);
    __builtin_amdgcn_s_setprio(0);
    BAR();
  }
#undef STG
#undef VMCNT
#undef BAR

  // ---- k-half reduction: swap so own cols live in acc[a][0..1] ----
  if (wk){
    #pragma unroll
    for (int a = 0; a < 8; a++){
      f32x4 t0 = acc[a][0]; acc[a][0] = acc[a][2]; acc[a][2] = t0;
      f32x4 t1 = acc[a][1]; acc[a][1] = acc[a][3]; acc[a][3] = t1;
    }
  }
  f32x4* red = (f32x4*)lds;
  const int pb = (wm*2 + wn)*2;
  const int wme = pb + (1 - wk);
  const int rme = pb + wk;
  #pragma unroll
  for (int a = 0; a < 8; a++){
    red[(wme*2 + 0)*64 + l] = acc[a][2];
    red[(wme*2 + 1)*64 + l] = acc[a][3];
    __builtin_amdgcn_s_barrier();
    acc[a][0] += red[(rme*2 + 0)*64 + l];
    acc[a][1] += red[(rme*2 + 1)*64 + l];
    __builtin_amdgcn_s_barrier();
  }

  if (MODE == 0){
    #pragma unroll
    for (int a = 0; a < 8; a++){
      #pragma unroll
      for (int jj = 0; jj < 2; jj++){
        int col   = (int)nbase + wn*64 + (wk*2 + jj)*16 + lr;
        int which = col >> 10;
        int h     = (col >> 6) & 15;
        int d     = col & 63;
        int m0    = (int)mbase + wm*128 + a*16 + lg*4;
        int b     = m0 >> 11, ns0 = m0 & 2047;
        int bh    = (b << 4) + h;
        f32x4 v   = (jj == 0) ? acc[a][0] : acc[a][1];
        if (which == 2){
          u16x4 pk;
          #pragma unroll
          for (int r = 0; r < 4; r++) pk[r] = f2b(v[r]);
          *(u16x4*)&vtb[((long)bh*64 + d)*2048 + ns0] = pk;
        } else {
          u16* dst  = (which == 0) ? qb : kb;
          float scl = (which == 0) ? QSCALE : 1.0f;
          #pragma unroll
          for (int r = 0; r < 4; r++)
            dst[((long)bh * 2048 + ns0 + r) * 64 + d] = f2b(v[r] * scl);
        }
      }
    }
  } else {
    #pragma unroll
    for (int a = 0; a < 8; a++){
      #pragma unroll
      for (int jj = 0; jj < 2; jj++){
        int c = (int)nbase + wn*64 + (wk*2 + jj)*16 + lr;
        float bv = bias[c];
        f32x4 v = (jj == 0) ? acc[a][0] : acc[a][1];
        #pragma unroll
        for (int r = 0; r < 4; r++){
          int m = (int)mbase + wm*128 + a*16 + lg*4 + r;
          outF[(long)m * N + c] = v[r] + bv;
        }
      }
    }
  }
}

// ------ flash attention: 2 waves x 64 q-rows (128 q/block), KV-tile 64 -------
// Same wave-level code as R8/R9 (64q/wave, 4 q-groups, shift-free softmax,
// sigma PV) but 128-thread blocks -> grid 1024 -> 4-5 independent blocks/CU
// (R9 had grid 512 = 2 barrier-coupled blocks/CU; serialization-limited).
__global__ __launch_bounds__(128, 4) void attn_fused(
    const u16* __restrict__ qb, const u16* __restrict__ kb,
    const u16* __restrict__ vtb, u16* __restrict__ ob)
{
  __shared__ u16 k_lds[2][64*64];
  __shared__ u16 vt_lds[2][64*64];
  const int t  = threadIdx.x;            // 0..127
  const int l  = t & 63, lr = l & 15, lg = l >> 4;
  const int w  = t >> 6;                 // 0..1
  const int bid = blockIdx.x;
  const int vid = (bid & 7) * 128 + (bid >> 3);     // XCD-contiguous (1024 wg)
  const int bh = vid >> 4, qt = vid & 15;
  const int qrow = qt*128 + w*64;
  const int h7 = lr & 7;

  // Q fragments for four 16-row groups
  const u16* Qp = qb + ((long)bh*2048 + qrow)*64;
  bf16x8 qf0[4], qf1[4];
  #pragma unroll
  for (int g = 0; g < 4; g++){
    qf0[g] = *(const bf16x8*)&Qp[(g*16+lr)*64 + lg*8];
    qf1[g] = *(const bf16x8*)&Qp[(g*16+lr)*64 + 32 + lg*8];
  }

  // staging (128 threads): rows r1 = t>>3 (0..15) + 16*i; chunk x = t&7
  // LDS[row][x] = G[row][x ^ (row&7)]
  const int r1 = t >> 3;
  const int cx = ((t & 7) ^ (r1 & 7)) * 8;
  const u16* Kp = kb  + (long)bh*2048*64;
  const u16* Vt = vtb + (long)bh*64*2048;
  int koffs[4], voffs[4];
  #pragma unroll
  for (int i = 0; i < 4; i++){
    koffs[i] = (r1 + 16*i)*64   + cx;
    voffs[i] = (r1 + 16*i)*2048 + cx;
  }

#define STAGE(kv, buf) do { \
    _Pragma("unroll") \
    for (int i_ = 0; i_ < 4; i_++){ \
      gload_lds16(Kp + (long)(kv)*64 + koffs[i_], &k_lds[buf][t*8 + i_*1024]); \
      gload_lds16(Vt + (kv) + voffs[i_],          &vt_lds[buf][t*8 + i_*1024]); \
    } \
  } while(0)

  f32x4 z = {0.f,0.f,0.f,0.f};
  f32x4 oacc[4][4];
  f32x2 sacc[4];
  #pragma unroll
  for (int g = 0; g < 4; g++){
    sacc[g] = (f32x2){0.f, 0.f};
    #pragma unroll
    for (int nt = 0; nt < 4; nt++) oacc[g][nt] = z;
  }

  STAGE(0, 0);
  for (int it = 0; it < 32; ++it){
    const int cur = it & 1;
    __syncthreads();                     // buf[cur] ready (barrier drains vmcnt)
    if (it < 31) STAGE((it+1)*64, cur^1);

    const u16* kl = k_lds[cur];
    const u16* vl = vt_lds[cur];

    // S^T: lane holds cols q = g*16+lr, rows k = k4*16 + lg*4 + r
    f32x4 st[4][4];
    __builtin_amdgcn_s_setprio(1);
    #pragma unroll
    for (int k4 = 0; k4 < 4; k4++){
      const int row = (k4*16 + lr)*64;
      bf16x8 kf0 = *(const bf16x8*)&kl[row + ((0+lg)^h7)*8];
      bf16x8 kf1 = *(const bf16x8*)&kl[row + ((4+lg)^h7)*8];
      #pragma unroll
      for (int g = 0; g < 4; g++){
        st[g][k4] = MFMA16(kf0, qf0[g], z);
        st[g][k4] = MFMA16(kf1, qf1[g], st[g][k4]);
      }
    }
    __builtin_amdgcn_s_setprio(0);

    // shift-free: P = 2^s; per-lane partial sums; pack to sigma A-fragments
    bf16x8 pa0[4], pa1[4];
    #pragma unroll
    for (int g = 0; g < 4; g++){
      u32 wv[4][2];
      #pragma unroll
      for (int k4 = 0; k4 < 4; k4++){
        f32x2 e0 = lo2(st[g][k4]), e1 = hi2(st[g][k4]);
        e0[0] = exp2_raw(e0[0]); e0[1] = exp2_raw(e0[1]);
        e1[0] = exp2_raw(e1[0]); e1[1] = exp2_raw(e1[1]);
        sacc[g] += e0 + e1;
        wv[k4][0] = cvt_pk_bf16(e0[0], e0[1]);
        wv[k4][1] = cvt_pk_bf16(e1[0], e1[1]);
      }
      union { u32 u[4]; bf16x8 v; } p0, p1;
      p0.u[0]=wv[0][0]; p0.u[1]=wv[0][1]; p0.u[2]=wv[1][0]; p0.u[3]=wv[1][1];
      p1.u[0]=wv[2][0]; p1.u[1]=wv[2][1]; p1.u[2]=wv[3][0]; p1.u[3]=wv[3][1];
      pa0[g] = p0.v; pa1[g] = p1.v;
    }

    // O += P V : V fragment shared by all 4 groups (8 MFMA per read pair)
    const int vhalf = (lg & 1) * 4;
    const int cA    = lg >> 1;
    #pragma unroll
    for (int nt = 0; nt < 4; nt++){
      const int rb = (nt*16 + lr)*64;
      u16x4 a0_ = *(const u16x4*)&vl[rb + ((cA     ^ h7)*8) + vhalf];
      u16x4 a1_ = *(const u16x4*)&vl[rb + (((cA+2) ^ h7)*8) + vhalf];
      u16x4 a2_ = *(const u16x4*)&vl[rb + (((cA+4) ^ h7)*8) + vhalf];
      u16x4 a3_ = *(const u16x4*)&vl[rb + (((cA+6) ^ h7)*8) + vhalf];
      u16x8 s0 = __builtin_shufflevector(a0_, a1_, 0,1,2,3,4,5,6,7);
      u16x8 s1 = __builtin_shufflevector(a2_, a3_, 0,1,2,3,4,5,6,7);
      __builtin_amdgcn_s_setprio(1);
      #pragma unroll
      for (int g = 0; g < 4; g++){
        oacc[g][nt] = MFMA16(pa0[g], *(bf16x8*)&s0, oacc[g][nt]);
        oacc[g][nt] = MFMA16(pa1[g], *(bf16x8*)&s1, oacc[g][nt]);
      }
      __builtin_amdgcn_s_setprio(0);
    }
  }
#undef STAGE

  const int b = bh >> 4, h = bh & 15;
  #pragma unroll
  for (int g = 0; g < 4; g++){
    float rs = sacc[g][0] + sacc[g][1];
    rs += __shfl_xor(rs, 16, 64);
    rs += __shfl_xor(rs, 32, 64);
    float linv = 1.0f / rs;
    #pragma unroll
    for (int r = 0; r < 4; r++){
      float lrr = __shfl(linv, lg*4 + r, 64);
      long m = (long)b*2048 + qrow + g*16 + lg*4 + r;
      #pragma unroll
      for (int nt = 0; nt < 4; nt++)
        ob[m*1024 + h*64 + nt*16 + lr] = f2b(oacc[g][nt][r] * lrr);
    }
  }
}

extern "C" void kernel_launch(void* const* d_in, const int* in_sizes, int n_in,
                              void* d_out, int out_size, void* d_ws, size_t ws_size,
                              hipStream_t stream)
{
  const float* x      = (const float*)d_in[0];
  const float* w_qkv  = (const float*)d_in[1];
  const float* w_proj = (const float*)d_in[2];
  const float* b_proj = (const float*)d_in[3];
  float* out = (float*)d_out;

  char* ws = (char*)d_ws;
  size_t off = 0;
  u16* xb     = (u16*)(ws + off);                 // 16MB, dead after GEMM1
  u16* obuf   = xb;                               // aliases xb
  off += (size_t)8192*1024*2;
  u16* wqkvt  = (u16*)(ws + off); off += (size_t)3072*1024*2;
  u16* wprojt = (u16*)(ws + off); off += (size_t)1024*1024*2;
  u16* qbuf   = (u16*)(ws + off); off += (size_t)64*2048*64*2;
  u16* kbuf   = (u16*)(ws + off); off += (size_t)64*2048*64*2;
  u16* vtb    = (u16*)(ws + off); off += (size_t)64*64*2048*2;

  hipFuncSetAttribute(reinterpret_cast<const void*>(&gemm8<0>),
                      hipFuncAttributeMaxDynamicSharedMemorySize, 147456);
  hipFuncSetAttribute(reinterpret_cast<const void*>(&gemm8<1>),
                      hipFuncAttributeMaxDynamicSharedMemorySize, 147456);

  cast_f32_bf16<<<2048, 256, 0, stream>>>(x, xb, (8192*1024)/4);
  tcast<<<dim3(96, 32), dim3(32, 8), 0, stream>>>(w_qkv, wqkvt, 1024, 3072);
  tcast<<<dim3(32, 32), dim3(32, 8), 0, stream>>>(w_proj, wprojt, 1024, 1024);

  gemm8<0><<<dim3(768), 512, 147456, stream>>>(xb, wqkvt, 8192, 3072, 1024,
                                               nullptr, nullptr, qbuf, kbuf, vtb);
  attn_fused<<<dim3(1024), 128, 0, stream>>>(qbuf, kbuf, vtb, obuf);
  gemm8<1><<<dim3(256), 512, 147456, stream>>>(obuf, wprojt, 8192, 1024, 1024,
                                               out, b_proj, nullptr, nullptr, nullptr);
}

// Round 11
// 190.600 us; speedup vs baseline: 1.1278x; 1.1278x over previous
//
#include <hip/hip_runtime.h>

typedef unsigned short u16;
typedef unsigned int   u32;
typedef __attribute__((ext_vector_type(2))) float    f32x2;
typedef __attribute__((ext_vector_type(4))) float    f32x4;
typedef __attribute__((ext_vector_type(8))) __bf16   bf16x8;
typedef __attribute__((ext_vector_type(8))) unsigned short u16x8;
typedef __attribute__((ext_vector_type(4))) unsigned short u16x4;
typedef __attribute__((ext_vector_type(4))) float    float4v;

#define MFMA16(a,b,c) __builtin_amdgcn_mfma_f32_16x16x32_bf16((a),(b),(c),0,0,0)
// softmax scale folded with log2(e): 0.125 * 1.4426950408889634
#define QSCALE 0.18033688011112042f

__device__ __forceinline__ u16 f2b(float f){
  union { float f; unsigned u; } v; v.f = f;
  return (u16)((v.u + 0x7fffu + ((v.u >> 16) & 1u)) >> 16);
}

__device__ __forceinline__ float b2f(u16 u){
  union { unsigned u; float f; } v; v.u = ((u32)u) << 16;
  return v.f;
}

__device__ __forceinline__ u32 cvt_pk_bf16(float lo, float hi){
  u32 r;
  asm("v_cvt_pk_bf16_f32 %0, %1, %2" : "=v"(r) : "v"(lo), "v"(hi));
  return r;
}

__device__ __forceinline__ float exp2_raw(float x){
  float r;
  asm("v_exp_f32 %0, %1" : "=v"(r) : "v"(x));
  return r;
}

__device__ __forceinline__ f32x2 lo2(f32x4 v){ return __builtin_shufflevector(v, v, 0, 1); }
__device__ __forceinline__ f32x2 hi2(f32x4 v){ return __builtin_shufflevector(v, v, 2, 3); }

__device__ __forceinline__ void gload_lds16(const void* g, void* l){
  __builtin_amdgcn_global_load_lds(
      (const __attribute__((address_space(1))) void*)g,
      (__attribute__((address_space(3))) void*)l, 16, 0, 0);
}

// ---------------- cast fp32 -> bf16 (elementwise, vectorized) ----------------
__global__ void cast_f32_bf16(const float* __restrict__ in, u16* __restrict__ out, int n4){
  int i = blockIdx.x * blockDim.x + threadIdx.x;
  int st = gridDim.x * blockDim.x;
  for (; i < n4; i += st){
    float4v v = ((const float4v*)in)[i];
    u16x4 o;
    o[0] = f2b(v[0]); o[1] = f2b(v[1]); o[2] = f2b(v[2]); o[3] = f2b(v[3]);
    ((u16x4*)out)[i] = o;
  }
}

// ------------- transpose + cast: src fp32 [R][C] -> dst bf16 [C][R] ----------
__global__ void tcast(const float* __restrict__ src, u16* __restrict__ dst, int R, int C){
  __shared__ float tile[32][33];
  int tx = threadIdx.x, ty = threadIdx.y;
  int c0 = blockIdx.x * 32, r0 = blockIdx.y * 32;
  #pragma unroll
  for (int i = 0; i < 4; i++)
    tile[ty + i*8][tx] = src[(long)(r0 + ty + i*8) * C + c0 + tx];
  __syncthreads();
  #pragma unroll
  for (int i = 0; i < 4; i++)
    dst[(long)(c0 + ty + i*8) * R + r0 + tx] = f2b(tile[tx][ty + i*8]);
}

// ====== k-split GEMM: C = A[M,K] @ Bt[N,K]^T, BM=256 BN=128, BK=64 ===========
// (unchanged from R9: 3-slot ring, vmcnt(6)/tile, XOR swizzle, XCD remap)
template<int MODE>
__global__ __launch_bounds__(512, 2) void gemm8(
    const u16* __restrict__ A, const u16* __restrict__ Bt,
    int M, int N, int K,
    float* __restrict__ outF, const float* __restrict__ bias,
    u16* __restrict__ qb, u16* __restrict__ kb, u16* __restrict__ vtb)
{
  extern __shared__ u16 lds[];
  u16* aL = lds;             // 3 slots x 16384 u16 (32KB)
  u16* bL = lds + 49152;     // 3 slots x  8192 u16 (16KB)

  const int t  = threadIdx.x;          // 0..511
  const int l  = t & 63, lr = l & 15, lg = l >> 4;
  const int w  = t >> 6;               // 0..7
  const int wm = w >> 2, wn = (w >> 1) & 1, wk = w & 1;
  const int bid = blockIdx.x;
  const int xcd = bid & 7, idx = bid >> 3;
  const long mbase = (long)(xcd*4 + (idx & 3)) * 256;
  const long nbase = (long)(idx >> 2) * 128;

  const int xr0 = t >> 3;
  const int xc  = t & 7;
  const int xswz = (xc ^ (xr0 & 7)) << 3;

#define STG(F_) do { \
    const int T_ = (F_) >> 2, h_ = (F_) & 3, slot_ = T_ % 3; \
    if ((h_ & 1) == 0){ const int ah = h_ >> 1; \
      const u16* g_ = A + (mbase + ah*128 + xr0)*(long)K + T_*64 + xswz; \
      u16* d_ = aL + slot_*16384 + ah*8192 + t*8; \
      gload_lds16(g_, d_); \
      gload_lds16(g_ + 64*(long)K, d_ + 4096); \
    } else { const int bh_ = h_ >> 1; \
      const u16* g_ = Bt + (nbase + bh_*64 + xr0)*(long)K + T_*64 + xswz; \
      gload_lds16(g_, bL + slot_*8192 + bh_*4096 + t*8); } \
  } while(0)

#define VMCNT(n) asm volatile("s_waitcnt vmcnt(" #n ")" ::: "memory")
#define BAR() __builtin_amdgcn_s_barrier()

  f32x4 z = {0.f,0.f,0.f,0.f};
  f32x4 acc[8][4];
  #pragma unroll
  for (int a = 0; a < 8; a++)
    #pragma unroll
    for (int j = 0; j < 4; j++) acc[a][j] = z;

  const int kc = wk*4;   // k-half chunk base for this wave

  STG(0); STG(1); STG(2); STG(3);
  STG(4); STG(5); STG(6); STG(7);
  VMCNT(6);
  BAR();

  for (int T = 0; T < 16; ++T){
    const int abuf = (T % 3) * 16384;
    const int bbuf = (T % 3) * 8192;
    bf16x8 afi[8], bfj[4];

    #pragma unroll
    for (int j = 0; j < 4; j++){
      const int rb = wn*64 + j*16 + lr;
      bfj[j] = *(const bf16x8*)&bL[bbuf + rb*64 + (((kc+lg)^(rb&7))<<3)];
    }
    #pragma unroll
    for (int i = 0; i < 8; i++){
      const int ra = wm*128 + i*16 + lr;
      afi[i] = *(const bf16x8*)&aL[abuf + ra*64 + (((kc+lg)^(ra&7))<<3)];
    }
    if (T < 14){
      STG(4*(T+2)); STG(4*(T+2)+1); STG(4*(T+2)+2); STG(4*(T+2)+3);
      VMCNT(6);
    } else if (T == 14){
      VMCNT(0);
    }
    BAR();
    __builtin_amdgcn_s_setprio(1);
    #pragma unroll
    for (int i = 0; i < 8; i++)
      #pragma unroll
      for (int j = 0; j < 4; j++)
        acc[i][j] = MFMA16(afi[i], bfj[j], acc[i][j]);
    __builtin_amdgcn_s_setprio(0);
    BAR();
  }
#undef STG
#undef VMCNT
#undef BAR

  // ---- k-half reduction: swap so own cols live in acc[a][0..1] ----
  if (wk){
    #pragma unroll
    for (int a = 0; a < 8; a++){
      f32x4 t0 = acc[a][0]; acc[a][0] = acc[a][2]; acc[a][2] = t0;
      f32x4 t1 = acc[a][1]; acc[a][1] = acc[a][3]; acc[a][3] = t1;
    }
  }
  f32x4* red = (f32x4*)lds;
  const int pb = (wm*2 + wn)*2;
  const int wme = pb + (1 - wk);
  const int rme = pb + wk;
  #pragma unroll
  for (int a = 0; a < 8; a++){
    red[(wme*2 + 0)*64 + l] = acc[a][2];
    red[(wme*2 + 1)*64 + l] = acc[a][3];
    __builtin_amdgcn_s_barrier();
    acc[a][0] += red[(rme*2 + 0)*64 + l];
    acc[a][1] += red[(rme*2 + 1)*64 + l];
    __builtin_amdgcn_s_barrier();
  }

  if (MODE == 0){
    #pragma unroll
    for (int a = 0; a < 8; a++){
      #pragma unroll
      for (int jj = 0; jj < 2; jj++){
        int col   = (int)nbase + wn*64 + (wk*2 + jj)*16 + lr;
        int which = col >> 10;
        int h     = (col >> 6) & 15;
        int d     = col & 63;
        int m0    = (int)mbase + wm*128 + a*16 + lg*4;
        int b     = m0 >> 11, ns0 = m0 & 2047;
        int bh    = (b << 4) + h;
        f32x4 v   = (jj == 0) ? acc[a][0] : acc[a][1];
        if (which == 2){
          u16x4 pk;
          #pragma unroll
          for (int r = 0; r < 4; r++) pk[r] = f2b(v[r]);
          *(u16x4*)&vtb[((long)bh*64 + d)*2048 + ns0] = pk;
        } else {
          u16* dst  = (which == 0) ? qb : kb;
          float scl = (which == 0) ? QSCALE : 1.0f;
          #pragma unroll
          for (int r = 0; r < 4; r++)
            dst[((long)bh * 2048 + ns0 + r) * 64 + d] = f2b(v[r] * scl);
        }
      }
    }
  } else {
    #pragma unroll
    for (int a = 0; a < 8; a++){
      #pragma unroll
      for (int jj = 0; jj < 2; jj++){
        int c = (int)nbase + wn*64 + (wk*2 + jj)*16 + lr;
        float bv = bias[c];
        f32x4 v = (jj == 0) ? acc[a][0] : acc[a][1];
        #pragma unroll
        for (int r = 0; r < 4; r++){
          int m = (int)mbase + wm*128 + a*16 + lg*4 + r;
          outF[(long)m * N + c] = v[r] + bv;
        }
      }
    }
  }
}

// ------ flash attention, KV-split x2: 4 waves x 64 q-rows, 1024 keys/block ---
// R9 wave-level code; each block handles half the KV range (16 tiles).
// Writes raw (unnormalized) partial O to po[half] (bf16, [8192][1024]) and
// partial row-sums to ls[half] (f32, [64][2048]). Shift-free softmax makes
// partials combine by pure addition. Grid 1024 -> 4 blocks/CU, 16 waves/CU.
__global__ __launch_bounds__(256, 2) void attn_fused(
    const u16* __restrict__ qb, const u16* __restrict__ kb,
    const u16* __restrict__ vtb,
    u16* __restrict__ po0, u16* __restrict__ po1, float* __restrict__ ls)
{
  __shared__ u16 k_lds[2][64*64];
  __shared__ u16 vt_lds[2][64*64];
  const int t  = threadIdx.x;            // 0..255
  const int l  = t & 63, lr = l & 15, lg = l >> 4;
  const int w  = t >> 6;                 // 0..3
  const int bid = blockIdx.x;
  const int vid = (bid & 7) * 128 + (bid >> 3);     // XCD-contiguous (1024 wg)
  const int bh   = vid >> 4;
  const int qt   = (vid >> 1) & 7;
  const int half = vid & 1;
  const int qrow = qt*256 + w*64;
  const int kvbase = half * 1024;
  const int h7 = lr & 7;

  u16* pob = half ? po1 : po0;
  float* lsb = ls + half * (64*2048);

  // Q fragments for four 16-row groups
  const u16* Qp = qb + ((long)bh*2048 + qrow)*64;
  bf16x8 qf0[4], qf1[4];
  #pragma unroll
  for (int g = 0; g < 4; g++){
    qf0[g] = *(const bf16x8*)&Qp[(g*16+lr)*64 + lg*8];
    qf1[g] = *(const bf16x8*)&Qp[(g*16+lr)*64 + 32 + lg*8];
  }

  const int r1 = t >> 3;
  const int cx = ((t & 7) ^ (r1 & 7)) * 8;
  const u16* Kp = kb  + (long)bh*2048*64;
  const u16* Vt = vtb + (long)bh*64*2048;
  const int koff0 = r1*64 + cx,        koff1 = (r1+32)*64 + cx;
  const int voff0 = r1*2048 + cx,      voff1 = (r1+32)*2048 + cx;

#define STAGE(kv, buf) do { \
    gload_lds16(Kp + (long)(kv)*64 + koff0, &k_lds[buf][t*8]); \
    gload_lds16(Kp + (long)(kv)*64 + koff1, &k_lds[buf][2048 + t*8]); \
    gload_lds16(Vt + (kv) + voff0, &vt_lds[buf][t*8]); \
    gload_lds16(Vt + (kv) + voff1, &vt_lds[buf][2048 + t*8]); \
  } while(0)

  f32x4 z = {0.f,0.f,0.f,0.f};
  f32x4 oacc[4][4];
  f32x2 sacc[4];
  #pragma unroll
  for (int g = 0; g < 4; g++){
    sacc[g] = (f32x2){0.f, 0.f};
    #pragma unroll
    for (int nt = 0; nt < 4; nt++) oacc[g][nt] = z;
  }

  STAGE(kvbase, 0);
  for (int it = 0; it < 16; ++it){
    const int cur = it & 1;
    __syncthreads();                     // buf[cur] ready (barrier drains vmcnt)
    if (it < 15) STAGE(kvbase + (it+1)*64, cur^1);

    const u16* kl = k_lds[cur];
    const u16* vl = vt_lds[cur];

    // S^T: lane holds cols q = g*16+lr, rows k = k4*16 + lg*4 + r
    f32x4 st[4][4];
    __builtin_amdgcn_s_setprio(1);
    #pragma unroll
    for (int k4 = 0; k4 < 4; k4++){
      const int row = (k4*16 + lr)*64;
      bf16x8 kf0 = *(const bf16x8*)&kl[row + ((0+lg)^h7)*8];
      bf16x8 kf1 = *(const bf16x8*)&kl[row + ((4+lg)^h7)*8];
      #pragma unroll
      for (int g = 0; g < 4; g++){
        st[g][k4] = MFMA16(kf0, qf0[g], z);
        st[g][k4] = MFMA16(kf1, qf1[g], st[g][k4]);
      }
    }
    __builtin_amdgcn_s_setprio(0);

    // shift-free: P = 2^s; per-lane partial sums; pack to sigma A-fragments
    bf16x8 pa0[4], pa1[4];
    #pragma unroll
    for (int g = 0; g < 4; g++){
      u32 wv[4][2];
      #pragma unroll
      for (int k4 = 0; k4 < 4; k4++){
        f32x2 e0 = lo2(st[g][k4]), e1 = hi2(st[g][k4]);
        e0[0] = exp2_raw(e0[0]); e0[1] = exp2_raw(e0[1]);
        e1[0] = exp2_raw(e1[0]); e1[1] = exp2_raw(e1[1]);
        sacc[g] += e0 + e1;
        wv[k4][0] = cvt_pk_bf16(e0[0], e0[1]);
        wv[k4][1] = cvt_pk_bf16(e1[0], e1[1]);
      }
      union { u32 u[4]; bf16x8 v; } p0, p1;
      p0.u[0]=wv[0][0]; p0.u[1]=wv[0][1]; p0.u[2]=wv[1][0]; p0.u[3]=wv[1][1];
      p1.u[0]=wv[2][0]; p1.u[1]=wv[2][1]; p1.u[2]=wv[3][0]; p1.u[3]=wv[3][1];
      pa0[g] = p0.v; pa1[g] = p1.v;
    }

    // O += P V : V fragment shared by all 4 groups (8 MFMA per read pair)
    const int vhalf = (lg & 1) * 4;
    const int cA    = lg >> 1;
    #pragma unroll
    for (int nt = 0; nt < 4; nt++){
      const int rb = (nt*16 + lr)*64;
      u16x4 a0_ = *(const u16x4*)&vl[rb + ((cA     ^ h7)*8) + vhalf];
      u16x4 a1_ = *(const u16x4*)&vl[rb + (((cA+2) ^ h7)*8) + vhalf];
      u16x4 a2_ = *(const u16x4*)&vl[rb + (((cA+4) ^ h7)*8) + vhalf];
      u16x4 a3_ = *(const u16x4*)&vl[rb + (((cA+6) ^ h7)*8) + vhalf];
      u16x8 s0 = __builtin_shufflevector(a0_, a1_, 0,1,2,3,4,5,6,7);
      u16x8 s1 = __builtin_shufflevector(a2_, a3_, 0,1,2,3,4,5,6,7);
      __builtin_amdgcn_s_setprio(1);
      #pragma unroll
      for (int g = 0; g < 4; g++){
        oacc[g][nt] = MFMA16(pa0[g], *(bf16x8*)&s0, oacc[g][nt]);
        oacc[g][nt] = MFMA16(pa1[g], *(bf16x8*)&s1, oacc[g][nt]);
      }
      __builtin_amdgcn_s_setprio(0);
    }
  }
#undef STAGE

  const int b = bh >> 4, h = bh & 15;
  #pragma unroll
  for (int g = 0; g < 4; g++){
    float rs = sacc[g][0] + sacc[g][1];
    rs += __shfl_xor(rs, 16, 64);
    rs += __shfl_xor(rs, 32, 64);
    if (lg == 0) lsb[bh*2048 + qrow + g*16 + lr] = rs;   // partial row-sum
    #pragma unroll
    for (int r = 0; r < 4; r++){
      long m = (long)b*2048 + qrow + g*16 + lg*4 + r;
      #pragma unroll
      for (int nt = 0; nt < 4; nt++)
        pob[m*1024 + h*64 + nt*16 + lr] = f2b(oacc[g][nt][r]);  // raw partial O
    }
  }
}

// ---- combine: ob = (po0 + po1) / (ls0 + ls1), bf16 [8192][1024] -------------
__global__ void attn_combine(const u16* __restrict__ po0, const u16* __restrict__ po1,
                             const float* __restrict__ ls, u16* __restrict__ ob)
{
  int gid = blockIdx.x * blockDim.x + threadIdx.x;
  int st  = gridDim.x * blockDim.x;
  for (; gid < 8192*128; gid += st){
    int m  = gid >> 7;
    int c8 = (gid & 127) * 8;
    int h  = c8 >> 6;
    int bh = ((m >> 11) << 4) + h;
    int q  = m & 2047;
    float inv = 1.0f / (ls[bh*2048 + q] + ls[64*2048 + bh*2048 + q]);
    u16x8 a = *(const u16x8*)&po0[(long)m*1024 + c8];
    u16x8 b = *(const u16x8*)&po1[(long)m*1024 + c8];
    u16x8 o;
    #pragma unroll
    for (int j = 0; j < 8; j++)
      o[j] = f2b((b2f(a[j]) + b2f(b[j])) * inv);
    *(u16x8*)&ob[(long)m*1024 + c8] = o;
  }
}

extern "C" void kernel_launch(void* const* d_in, const int* in_sizes, int n_in,
                              void* d_out, int out_size, void* d_ws, size_t ws_size,
                              hipStream_t stream)
{
  const float* x      = (const float*)d_in[0];
  const float* w_qkv  = (const float*)d_in[1];
  const float* w_proj = (const float*)d_in[2];
  const float* b_proj = (const float*)d_in[3];
  float* out = (float*)d_out;

  char* ws = (char*)d_ws;
  size_t off = 0;
  u16* xb     = (u16*)(ws + off);                 // 16MB: cast out / gemm1 in
  u16* po0    = xb;                               // aliases xb (dead after gemm1)
  off += (size_t)8192*1024*2;
  u16* wqkvt  = (u16*)(ws + off); off += (size_t)3072*1024*2;
  u16* wprojt = (u16*)(ws + off); off += (size_t)1024*1024*2;
  u16* qbuf   = (u16*)(ws + off); off += (size_t)64*2048*64*2;
  u16* obuf   = qbuf;                             // aliases qbuf (dead after attn)
  u16* kbuf   = (u16*)(ws + off); off += (size_t)64*2048*64*2;
  u16* vtb    = (u16*)(ws + off); off += (size_t)64*64*2048*2;
  u16* po1    = (u16*)(ws + off); off += (size_t)8192*1024*2;
  float* ls   = (float*)(ws + off); off += (size_t)2*64*2048*4;

  hipFuncSetAttribute(reinterpret_cast<const void*>(&gemm8<0>),
                      hipFuncAttributeMaxDynamicSharedMemorySize, 147456);
  hipFuncSetAttribute(reinterpret_cast<const void*>(&gemm8<1>),
                      hipFuncAttributeMaxDynamicSharedMemorySize, 147456);

  cast_f32_bf16<<<2048, 256, 0, stream>>>(x, xb, (8192*1024)/4);
  tcast<<<dim3(96, 32), dim3(32, 8), 0, stream>>>(w_qkv, wqkvt, 1024, 3072);
  tcast<<<dim3(32, 32), dim3(32, 8), 0, stream>>>(w_proj, wprojt, 1024, 1024);

  gemm8<0><<<dim3(768), 512, 147456, stream>>>(xb, wqkvt, 8192, 3072, 1024,
                                               nullptr, nullptr, qbuf, kbuf, vtb);
  attn_fused<<<dim3(1024), 256, 0, stream>>>(qbuf, kbuf, vtb, po0, po1, ls);
  attn_combine<<<dim3(2048), 256, 0, stream>>>(po0, po1, ls, obuf);
  gemm8<1><<<dim3(256), 512, 147456, stream>>>(obuf, wprojt, 8192, 1024, 1024,
                                               out, b_proj, nullptr, nullptr, nullptr);
}

// Round 14
// 183.083 us; speedup vs baseline: 1.1741x; 1.0411x over previous
//
#include <hip/hip_runtime.h>

typedef unsigned short u16;
typedef unsigned int   u32;
typedef __attribute__((ext_vector_type(2))) float    f32x2;
typedef __attribute__((ext_vector_type(4))) float    f32x4;
typedef __attribute__((ext_vector_type(8))) __bf16   bf16x8;
typedef __attribute__((ext_vector_type(8))) unsigned short u16x8;
typedef __attribute__((ext_vector_type(4))) unsigned short u16x4;
typedef __attribute__((ext_vector_type(4))) float    float4v;

#define MFMA16(a,b,c) __builtin_amdgcn_mfma_f32_16x16x32_bf16((a),(b),(c),0,0,0)
// softmax scale folded with log2(e): 0.125 * 1.4426950408889634
#define QSCALE 0.18033688011112042f

__device__ __forceinline__ u16 f2b(float f){
  union { float f; unsigned u; } v; v.f = f;
  return (u16)((v.u + 0x7fffu + ((v.u >> 16) & 1u)) >> 16);
}

__device__ __forceinline__ u32 cvt_pk_bf16(float lo, float hi){
  u32 r;
  asm("v_cvt_pk_bf16_f32 %0, %1, %2" : "=v"(r) : "v"(lo), "v"(hi));
  return r;
}

__device__ __forceinline__ float exp2_raw(float x){
  float r;
  asm("v_exp_f32 %0, %1" : "=v"(r) : "v"(x));
  return r;
}

__device__ __forceinline__ f32x2 lo2(f32x4 v){ return __builtin_shufflevector(v, v, 0, 1); }
__device__ __forceinline__ f32x2 hi2(f32x4 v){ return __builtin_shufflevector(v, v, 2, 3); }

__device__ __forceinline__ void gload_lds16(const void* g, void* l){
  __builtin_amdgcn_global_load_lds(
      (const __attribute__((address_space(1))) void*)g,
      (__attribute__((address_space(3))) void*)l, 16, 0, 0);
}

// ---------------- cast fp32 -> bf16 (elementwise, vectorized) ----------------
__global__ void cast_f32_bf16(const float* __restrict__ in, u16* __restrict__ out, int n4){
  int i = blockIdx.x * blockDim.x + threadIdx.x;
  int st = gridDim.x * blockDim.x;
  for (; i < n4; i += st){
    float4v v = ((const float4v*)in)[i];
    u16x4 o;
    o[0] = f2b(v[0]); o[1] = f2b(v[1]); o[2] = f2b(v[2]); o[3] = f2b(v[3]);
    ((u16x4*)out)[i] = o;
  }
}

// ------------- transpose + cast: src fp32 [R][C] -> dst bf16 [C][R] ----------
__global__ void tcast(const float* __restrict__ src, u16* __restrict__ dst, int R, int C){
  __shared__ float tile[32][33];
  int tx = threadIdx.x, ty = threadIdx.y;
  int c0 = blockIdx.x * 32, r0 = blockIdx.y * 32;
  #pragma unroll
  for (int i = 0; i < 4; i++)
    tile[ty + i*8][tx] = src[(long)(r0 + ty + i*8) * C + c0 + tx];
  __syncthreads();
  #pragma unroll
  for (int i = 0; i < 4; i++)
    dst[(long)(c0 + ty + i*8) * R + r0 + tx] = f2b(tile[tx][ty + i*8]);
}

// ====== k-split GEMM: C = A[M,K] @ Bt[N,K]^T, BM=256 BN=128, BK=64 ===========
// (unchanged from R9: 3-slot ring, vmcnt(6)/tile, XOR swizzle, XCD remap)
template<int MODE>
__global__ __launch_bounds__(512, 2) void gemm8(
    const u16* __restrict__ A, const u16* __restrict__ Bt,
    int M, int N, int K,
    float* __restrict__ outF, const float* __restrict__ bias,
    u16* __restrict__ qb, u16* __restrict__ kb, u16* __restrict__ vtb)
{
  extern __shared__ u16 lds[];
  u16* aL = lds;             // 3 slots x 16384 u16 (32KB)
  u16* bL = lds + 49152;     // 3 slots x  8192 u16 (16KB)

  const int t  = threadIdx.x;          // 0..511
  const int l  = t & 63, lr = l & 15, lg = l >> 4;
  const int w  = t >> 6;               // 0..7
  const int wm = w >> 2, wn = (w >> 1) & 1, wk = w & 1;
  const int bid = blockIdx.x;
  const int xcd = bid & 7, idx = bid >> 3;
  const long mbase = (long)(xcd*4 + (idx & 3)) * 256;
  const long nbase = (long)(idx >> 2) * 128;

  const int xr0 = t >> 3;
  const int xc  = t & 7;
  const int xswz = (xc ^ (xr0 & 7)) << 3;

#define STG(F_) do { \
    const int T_ = (F_) >> 2, h_ = (F_) & 3, slot_ = T_ % 3; \
    if ((h_ & 1) == 0){ const int ah = h_ >> 1; \
      const u16* g_ = A + (mbase + ah*128 + xr0)*(long)K + T_*64 + xswz; \
      u16* d_ = aL + slot_*16384 + ah*8192 + t*8; \
      gload_lds16(g_, d_); \
      gload_lds16(g_ + 64*(long)K, d_ + 4096); \
    } else { const int bh_ = h_ >> 1; \
      const u16* g_ = Bt + (nbase + bh_*64 + xr0)*(long)K + T_*64 + xswz; \
      gload_lds16(g_, bL + slot_*8192 + bh_*4096 + t*8); } \
  } while(0)

#define VMCNT(n) asm volatile("s_waitcnt vmcnt(" #n ")" ::: "memory")
#define BAR() __builtin_amdgcn_s_barrier()

  f32x4 z = {0.f,0.f,0.f,0.f};
  f32x4 acc[8][4];
  #pragma unroll
  for (int a = 0; a < 8; a++)
    #pragma unroll
    for (int j = 0; j < 4; j++) acc[a][j] = z;

  const int kc = wk*4;   // k-half chunk base for this wave

  STG(0); STG(1); STG(2); STG(3);
  STG(4); STG(5); STG(6); STG(7);
  VMCNT(6);
  BAR();

  for (int T = 0; T < 16; ++T){
    const int abuf = (T % 3) * 16384;
    const int bbuf = (T % 3) * 8192;
    bf16x8 afi[8], bfj[4];

    #pragma unroll
    for (int j = 0; j < 4; j++){
      const int rb = wn*64 + j*16 + lr;
      bfj[j] = *(const bf16x8*)&bL[bbuf + rb*64 + (((kc+lg)^(rb&7))<<3)];
    }
    #pragma unroll
    for (int i = 0; i < 8; i++){
      const int ra = wm*128 + i*16 + lr;
      afi[i] = *(const bf16x8*)&aL[abuf + ra*64 + (((kc+lg)^(ra&7))<<3)];
    }
    if (T < 14){
      STG(4*(T+2)); STG(4*(T+2)+1); STG(4*(T+2)+2); STG(4*(T+2)+3);
      VMCNT(6);
    } else if (T == 14){
      VMCNT(0);
    }
    BAR();
    __builtin_amdgcn_s_setprio(1);
    #pragma unroll
    for (int i = 0; i < 8; i++)
      #pragma unroll
      for (int j = 0; j < 4; j++)
        acc[i][j] = MFMA16(afi[i], bfj[j], acc[i][j]);
    __builtin_amdgcn_s_setprio(0);
    BAR();
  }
#undef STG
#undef VMCNT
#undef BAR

  // ---- k-half reduction: swap so own cols live in acc[a][0..1] ----
  if (wk){
    #pragma unroll
    for (int a = 0; a < 8; a++){
      f32x4 t0 = acc[a][0]; acc[a][0] = acc[a][2]; acc[a][2] = t0;
      f32x4 t1 = acc[a][1]; acc[a][1] = acc[a][3]; acc[a][3] = t1;
    }
  }
  f32x4* red = (f32x4*)lds;
  const int pb = (wm*2 + wn)*2;
  const int wme = pb + (1 - wk);
  const int rme = pb + wk;
  #pragma unroll
  for (int a = 0; a < 8; a++){
    red[(wme*2 + 0)*64 + l] = acc[a][2];
    red[(wme*2 + 1)*64 + l] = acc[a][3];
    __builtin_amdgcn_s_barrier();
    acc[a][0] += red[(rme*2 + 0)*64 + l];
    acc[a][1] += red[(rme*2 + 1)*64 + l];
    __builtin_amdgcn_s_barrier();
  }

  if (MODE == 0){
    #pragma unroll
    for (int a = 0; a < 8; a++){
      #pragma unroll
      for (int jj = 0; jj < 2; jj++){
        int col   = (int)nbase + wn*64 + (wk*2 + jj)*16 + lr;
        int which = col >> 10;
        int h     = (col >> 6) & 15;
        int d     = col & 63;
        int m0    = (int)mbase + wm*128 + a*16 + lg*4;
        int b     = m0 >> 11, ns0 = m0 & 2047;
        int bh    = (b << 4) + h;
        f32x4 v   = (jj == 0) ? acc[a][0] : acc[a][1];
        if (which == 2){
          u16x4 pk;
          #pragma unroll
          for (int r = 0; r < 4; r++) pk[r] = f2b(v[r]);
          *(u16x4*)&vtb[((long)bh*64 + d)*2048 + ns0] = pk;
        } else {
          u16* dst  = (which == 0) ? qb : kb;
          float scl = (which == 0) ? QSCALE : 1.0f;
          #pragma unroll
          for (int r = 0; r < 4; r++)
            dst[((long)bh * 2048 + ns0 + r) * 64 + d] = f2b(v[r] * scl);
        }
      }
    }
  } else {
    #pragma unroll
    for (int a = 0; a < 8; a++){
      #pragma unroll
      for (int jj = 0; jj < 2; jj++){
        int c = (int)nbase + wn*64 + (wk*2 + jj)*16 + lr;
        float bv = bias[c];
        f32x4 v = (jj == 0) ? acc[a][0] : acc[a][1];
        #pragma unroll
        for (int r = 0; r < 4; r++){
          int m = (int)mbase + wm*128 + a*16 + lg*4 + r;
          outF[(long)m * N + c] = v[r] + bv;
        }
      }
    }
  }
}

// ------ flash attention: 4 waves x 64 q-rows (256 q/block), KV-tile 64 -------
// R9-exact structure (2-slot K+V, STAGE both per iter, barrier per iter).
// Only change vs R9: PV's 16 ds_read_b64 V-fragment loads are hoisted to
// directly after QK, into registers (vs0/vs1), BEFORE the softmax -- their
// LDS latency hides under SM's VALU block; PV is then MFMA-only.
__global__ __launch_bounds__(256, 2) void attn_fused(
    const u16* __restrict__ qb, const u16* __restrict__ kb,
    const u16* __restrict__ vtb, u16* __restrict__ ob)
{
  __shared__ u16 k_lds[2][64*64];
  __shared__ u16 vt_lds[2][64*64];
  const int t  = threadIdx.x;            // 0..255
  const int l  = t & 63, lr = l & 15, lg = l >> 4;
  const int w  = t >> 6;                 // 0..3
  const int bid = blockIdx.x;
  const int vid = (bid & 7) * 64 + (bid >> 3);      // XCD-contiguous (512 wg)
  const int bh = vid >> 3, qt = vid & 7;
  const int qrow = qt*256 + w*64;
  const int h7 = lr & 7;

  // Q fragments for four 16-row groups
  const u16* Qp = qb + ((long)bh*2048 + qrow)*64;
  bf16x8 qf0[4], qf1[4];
  #pragma unroll
  for (int g = 0; g < 4; g++){
    qf0[g] = *(const bf16x8*)&Qp[(g*16+lr)*64 + lg*8];
    qf1[g] = *(const bf16x8*)&Qp[(g*16+lr)*64 + 32 + lg*8];
  }

  const int r1 = t >> 3;
  const int cx = ((t & 7) ^ (r1 & 7)) * 8;
  const u16* Kp = kb  + (long)bh*2048*64;
  const u16* Vt = vtb + (long)bh*64*2048;
  const int koff0 = r1*64 + cx,        koff1 = (r1+32)*64 + cx;
  const int voff0 = r1*2048 + cx,      voff1 = (r1+32)*2048 + cx;

#define STAGE(kv, buf) do { \
    gload_lds16(Kp + (long)(kv)*64 + koff0, &k_lds[buf][t*8]); \
    gload_lds16(Kp + (long)(kv)*64 + koff1, &k_lds[buf][2048 + t*8]); \
    gload_lds16(Vt + (kv) + voff0, &vt_lds[buf][t*8]); \
    gload_lds16(Vt + (kv) + voff1, &vt_lds[buf][2048 + t*8]); \
  } while(0)

  f32x4 z = {0.f,0.f,0.f,0.f};
  f32x4 oacc[4][4];
  f32x2 sacc[4];
  #pragma unroll
  for (int g = 0; g < 4; g++){
    sacc[g] = (f32x2){0.f, 0.f};
    #pragma unroll
    for (int nt = 0; nt < 4; nt++) oacc[g][nt] = z;
  }

  STAGE(0, 0);
  for (int it = 0; it < 32; ++it){
    const int cur = it & 1;
    __syncthreads();                     // buf[cur] ready (barrier drains vmcnt)
    if (it < 31) STAGE((it+1)*64, cur^1);

    const u16* kl = k_lds[cur];
    const u16* vl = vt_lds[cur];

    // S^T: lane holds cols q = g*16+lr, rows k = k4*16 + lg*4 + r
    f32x4 st[4][4];
    __builtin_amdgcn_s_setprio(1);
    #pragma unroll
    for (int k4 = 0; k4 < 4; k4++){
      const int row = (k4*16 + lr)*64;
      bf16x8 kf0 = *(const bf16x8*)&kl[row + ((0+lg)^h7)*8];
      bf16x8 kf1 = *(const bf16x8*)&kl[row + ((4+lg)^h7)*8];
      #pragma unroll
      for (int g = 0; g < 4; g++){
        st[g][k4] = MFMA16(kf0, qf0[g], z);
        st[g][k4] = MFMA16(kf1, qf1[g], st[g][k4]);
      }
    }
    __builtin_amdgcn_s_setprio(0);

    // V fragments -> registers NOW (latency hides under softmax VALU below)
    u16x8 vs0[4], vs1[4];
    {
      const int vhalf = (lg & 1) * 4;
      const int cA    = lg >> 1;
      #pragma unroll
      for (int nt = 0; nt < 4; nt++){
        const int rb = (nt*16 + lr)*64;
        u16x4 a0_ = *(const u16x4*)&vl[rb + ((cA     ^ h7)*8) + vhalf];
        u16x4 a1_ = *(const u16x4*)&vl[rb + (((cA+2) ^ h7)*8) + vhalf];
        u16x4 a2_ = *(const u16x4*)&vl[rb + (((cA+4) ^ h7)*8) + vhalf];
        u16x4 a3_ = *(const u16x4*)&vl[rb + (((cA+6) ^ h7)*8) + vhalf];
        vs0[nt] = __builtin_shufflevector(a0_, a1_, 0,1,2,3,4,5,6,7);
        vs1[nt] = __builtin_shufflevector(a2_, a3_, 0,1,2,3,4,5,6,7);
      }
    }

    // shift-free softmax: P = 2^s; per-lane partial sums; sigma A-fragments
    bf16x8 pa0[4], pa1[4];
    #pragma unroll
    for (int g = 0; g < 4; g++){
      u32 wv[4][2];
      #pragma unroll
      for (int k4 = 0; k4 < 4; k4++){
        f32x2 e0 = lo2(st[g][k4]), e1 = hi2(st[g][k4]);
        e0[0] = exp2_raw(e0[0]); e0[1] = exp2_raw(e0[1]);
        e1[0] = exp2_raw(e1[0]); e1[1] = exp2_raw(e1[1]);
        sacc[g] += e0 + e1;
        wv[k4][0] = cvt_pk_bf16(e0[0], e0[1]);
        wv[k4][1] = cvt_pk_bf16(e1[0], e1[1]);
      }
      union { u32 u[4]; bf16x8 v; } p0, p1;
      p0.u[0]=wv[0][0]; p0.u[1]=wv[0][1]; p0.u[2]=wv[1][0]; p0.u[3]=wv[1][1];
      p1.u[0]=wv[2][0]; p1.u[1]=wv[2][1]; p1.u[2]=wv[3][0]; p1.u[3]=wv[3][1];
      pa0[g] = p0.v; pa1[g] = p1.v;
    }

    // O += P V : MFMA-only (V fragments already in registers)
    __builtin_amdgcn_s_setprio(1);
    #pragma unroll
    for (int nt = 0; nt < 4; nt++){
      #pragma unroll
      for (int g = 0; g < 4; g++){
        oacc[g][nt] = MFMA16(pa0[g], *(bf16x8*)&vs0[nt], oacc[g][nt]);
        oacc[g][nt] = MFMA16(pa1[g], *(bf16x8*)&vs1[nt], oacc[g][nt]);
      }
    }
    __builtin_amdgcn_s_setprio(0);
  }
#undef STAGE

  const int b = bh >> 4, h = bh & 15;
  #pragma unroll
  for (int g = 0; g < 4; g++){
    float rs = sacc[g][0] + sacc[g][1];
    rs += __shfl_xor(rs, 16, 64);
    rs += __shfl_xor(rs, 32, 64);
    float linv = 1.0f / rs;
    #pragma unroll
    for (int r = 0; r < 4; r++){
      float lrr = __shfl(linv, lg*4 + r, 64);
      long m = (long)b*2048 + qrow + g*16 + lg*4 + r;
      #pragma unroll
      for (int nt = 0; nt < 4; nt++)
        ob[m*1024 + h*64 + nt*16 + lr] = f2b(oacc[g][nt][r] * lrr);
    }
  }
}

extern "C" void kernel_launch(void* const* d_in, const int* in_sizes, int n_in,
                              void* d_out, int out_size, void* d_ws, size_t ws_size,
                              hipStream_t stream)
{
  const float* x      = (const float*)d_in[0];
  const float* w_qkv  = (const float*)d_in[1];
  const float* w_proj = (const float*)d_in[2];
  const float* b_proj = (const float*)d_in[3];
  float* out = (float*)d_out;

  char* ws = (char*)d_ws;
  size_t off = 0;
  u16* xb     = (u16*)(ws + off);                 // 16MB: cast out / gemm1 in
  u16* obuf   = xb;                               // aliases xb (dead after gemm1)
  off += (size_t)8192*1024*2;
  u16* wqkvt  = (u16*)(ws + off); off += (size_t)3072*1024*2;
  u16* wprojt = (u16*)(ws + off); off += (size_t)1024*1024*2;
  u16* qbuf   = (u16*)(ws + off); off += (size_t)64*2048*64*2;
  u16* kbuf   = (u16*)(ws + off); off += (size_t)64*2048*64*2;
  u16* vtb    = (u16*)(ws + off); off += (size_t)64*64*2048*2;

  hipFuncSetAttribute(reinterpret_cast<const void*>(&gemm8<0>),
                      hipFuncAttributeMaxDynamicSharedMemorySize, 147456);
  hipFuncSetAttribute(reinterpret_cast<const void*>(&gemm8<1>),
                      hipFuncAttributeMaxDynamicSharedMemorySize, 147456);

  cast_f32_bf16<<<2048, 256, 0, stream>>>(x, xb, (8192*1024)/4);
  tcast<<<dim3(96, 32), dim3(32, 8), 0, stream>>>(w_qkv, wqkvt, 1024, 3072);
  tcast<<<dim3(32, 32), dim3(32, 8), 0, stream>>>(w_proj, wprojt, 1024, 1024);

  gemm8<0><<<dim3(768), 512, 147456, stream>>>(xb, wqkvt, 8192, 3072, 1024,
                                               nullptr, nullptr, qbuf, kbuf, vtb);
  attn_fused<<<dim3(512), 256, 0, stream>>>(qbuf, kbuf, vtb, obuf);
  gemm8<1><<<dim3(256), 512, 147456, stream>>>(obuf, wprojt, 8192, 1024, 1024,
                                               out, b_proj, nullptr, nullptr, nullptr);
}

// Round 15
// 176.027 us; speedup vs baseline: 1.2212x; 1.0401x over previous
//
#include <hip/hip_runtime.h>

typedef unsigned short u16;
typedef unsigned int   u32;
typedef __attribute__((ext_vector_type(2))) float    f32x2;
typedef __attribute__((ext_vector_type(4))) float    f32x4;
typedef __attribute__((ext_vector_type(8))) __bf16   bf16x8;
typedef __attribute__((ext_vector_type(8))) unsigned short u16x8;
typedef __attribute__((ext_vector_type(4))) unsigned short u16x4;
typedef __attribute__((ext_vector_type(4))) float    float4v;

#define MFMA16(a,b,c) __builtin_amdgcn_mfma_f32_16x16x32_bf16((a),(b),(c),0,0,0)
// softmax scale folded with log2(e): 0.125 * 1.4426950408889634
#define QSCALE 0.18033688011112042f

__device__ __forceinline__ u16 f2b(float f){
  union { float f; unsigned u; } v; v.f = f;
  return (u16)((v.u + 0x7fffu + ((v.u >> 16) & 1u)) >> 16);
}

__device__ __forceinline__ u32 cvt_pk_bf16(float lo, float hi){
  u32 r;
  asm("v_cvt_pk_bf16_f32 %0, %1, %2" : "=v"(r) : "v"(lo), "v"(hi));
  return r;
}

__device__ __forceinline__ float exp2_raw(float x){
  float r;
  asm("v_exp_f32 %0, %1" : "=v"(r) : "v"(x));
  return r;
}

__device__ __forceinline__ f32x2 lo2(f32x4 v){ return __builtin_shufflevector(v, v, 0, 1); }
__device__ __forceinline__ f32x2 hi2(f32x4 v){ return __builtin_shufflevector(v, v, 2, 3); }

__device__ __forceinline__ void gload_lds16(const void* g, void* l){
  __builtin_amdgcn_global_load_lds(
      (const __attribute__((address_space(1))) void*)g,
      (__attribute__((address_space(3))) void*)l, 16, 0, 0);
}

// ---- fused prep: blocks [0,2048) cast x->bf16; [2048,5120) tcast w_qkv;
// ---- [5120,6144) tcast w_proj.  Bodies identical to the verified kernels.
__global__ __launch_bounds__(256) void prep(
    const float* __restrict__ x,      u16* __restrict__ xb,
    const float* __restrict__ wqkv,   u16* __restrict__ wqkvt,
    const float* __restrict__ wproj,  u16* __restrict__ wprojt)
{
  __shared__ float tile[32][33];
  const int bid = blockIdx.x;
  const int t   = threadIdx.x;

  if (bid < 2048){
    // cast fp32 -> bf16, vectorized, 4 grid-stride iters
    const int n4 = (8192*1024)/4;
    int i = bid * 256 + t;
    const int st = 2048 * 256;
    for (; i < n4; i += st){
      float4v v = ((const float4v*)x)[i];
      u16x4 o;
      o[0] = f2b(v[0]); o[1] = f2b(v[1]); o[2] = f2b(v[2]); o[3] = f2b(v[3]);
      ((u16x4*)xb)[i] = o;
    }
    return;
  }

  // transpose+cast region
  const float* src; u16* dst; int R, C, bx, by;
  if (bid < 5120){
    int rel = bid - 2048;
    src = wqkv; dst = wqkvt; R = 1024; C = 3072;
    bx = rel % 96; by = rel / 96;
  } else {
    int rel = bid - 5120;
    src = wproj; dst = wprojt; R = 1024; C = 1024;
    bx = rel % 32; by = rel / 32;
  }
  const int tx = t & 31, ty = t >> 5;
  const int c0 = bx * 32, r0 = by * 32;
  #pragma unroll
  for (int i = 0; i < 4; i++)
    tile[ty + i*8][tx] = src[(long)(r0 + ty + i*8) * C + c0 + tx];
  __syncthreads();
  #pragma unroll
  for (int i = 0; i < 4; i++)
    dst[(long)(c0 + ty + i*8) * R + r0 + tx] = f2b(tile[tx][ty + i*8]);
}

// ====== k-split GEMM: C = A[M,K] @ Bt[N,K]^T, BM=256 BN=128, BK=64 ===========
// (unchanged from R9: 3-slot ring, vmcnt(6)/tile, XOR swizzle, XCD remap)
template<int MODE>
__global__ __launch_bounds__(512, 2) void gemm8(
    const u16* __restrict__ A, const u16* __restrict__ Bt,
    int M, int N, int K,
    float* __restrict__ outF, const float* __restrict__ bias,
    u16* __restrict__ qb, u16* __restrict__ kb, u16* __restrict__ vtb)
{
  extern __shared__ u16 lds[];
  u16* aL = lds;             // 3 slots x 16384 u16 (32KB)
  u16* bL = lds + 49152;     // 3 slots x  8192 u16 (16KB)

  const int t  = threadIdx.x;          // 0..511
  const int l  = t & 63, lr = l & 15, lg = l >> 4;
  const int w  = t >> 6;               // 0..7
  const int wm = w >> 2, wn = (w >> 1) & 1, wk = w & 1;
  const int bid = blockIdx.x;
  const int xcd = bid & 7, idx = bid >> 3;
  const long mbase = (long)(xcd*4 + (idx & 3)) * 256;
  const long nbase = (long)(idx >> 2) * 128;

  const int xr0 = t >> 3;
  const int xc  = t & 7;
  const int xswz = (xc ^ (xr0 & 7)) << 3;

#define STG(F_) do { \
    const int T_ = (F_) >> 2, h_ = (F_) & 3, slot_ = T_ % 3; \
    if ((h_ & 1) == 0){ const int ah = h_ >> 1; \
      const u16* g_ = A + (mbase + ah*128 + xr0)*(long)K + T_*64 + xswz; \
      u16* d_ = aL + slot_*16384 + ah*8192 + t*8; \
      gload_lds16(g_, d_); \
      gload_lds16(g_ + 64*(long)K, d_ + 4096); \
    } else { const int bh_ = h_ >> 1; \
      const u16* g_ = Bt + (nbase + bh_*64 + xr0)*(long)K + T_*64 + xswz; \
      gload_lds16(g_, bL + slot_*8192 + bh_*4096 + t*8); } \
  } while(0)

#define VMCNT(n) asm volatile("s_waitcnt vmcnt(" #n ")" ::: "memory")
#define BAR() __builtin_amdgcn_s_barrier()

  f32x4 z = {0.f,0.f,0.f,0.f};
  f32x4 acc[8][4];
  #pragma unroll
  for (int a = 0; a < 8; a++)
    #pragma unroll
    for (int j = 0; j < 4; j++) acc[a][j] = z;

  const int kc = wk*4;   // k-half chunk base for this wave

  STG(0); STG(1); STG(2); STG(3);
  STG(4); STG(5); STG(6); STG(7);
  VMCNT(6);
  BAR();

  for (int T = 0; T < 16; ++T){
    const int abuf = (T % 3) * 16384;
    const int bbuf = (T % 3) * 8192;
    bf16x8 afi[8], bfj[4];

    #pragma unroll
    for (int j = 0; j < 4; j++){
      const int rb = wn*64 + j*16 + lr;
      bfj[j] = *(const bf16x8*)&bL[bbuf + rb*64 + (((kc+lg)^(rb&7))<<3)];
    }
    #pragma unroll
    for (int i = 0; i < 8; i++){
      const int ra = wm*128 + i*16 + lr;
      afi[i] = *(const bf16x8*)&aL[abuf + ra*64 + (((kc+lg)^(ra&7))<<3)];
    }
    if (T < 14){
      STG(4*(T+2)); STG(4*(T+2)+1); STG(4*(T+2)+2); STG(4*(T+2)+3);
      VMCNT(6);
    } else if (T == 14){
      VMCNT(0);
    }
    BAR();
    __builtin_amdgcn_s_setprio(1);
    #pragma unroll
    for (int i = 0; i < 8; i++)
      #pragma unroll
      for (int j = 0; j < 4; j++)
        acc[i][j] = MFMA16(afi[i], bfj[j], acc[i][j]);
    __builtin_amdgcn_s_setprio(0);
    BAR();
  }
#undef STG
#undef VMCNT
#undef BAR

  // ---- k-half reduction: swap so own cols live in acc[a][0..1] ----
  if (wk){
    #pragma unroll
    for (int a = 0; a < 8; a++){
      f32x4 t0 = acc[a][0]; acc[a][0] = acc[a][2]; acc[a][2] = t0;
      f32x4 t1 = acc[a][1]; acc[a][1] = acc[a][3]; acc[a][3] = t1;
    }
  }
  f32x4* red = (f32x4*)lds;
  const int pb = (wm*2 + wn)*2;
  const int wme = pb + (1 - wk);
  const int rme = pb + wk;
  #pragma unroll
  for (int a = 0; a < 8; a++){
    red[(wme*2 + 0)*64 + l] = acc[a][2];
    red[(wme*2 + 1)*64 + l] = acc[a][3];
    __builtin_amdgcn_s_barrier();
    acc[a][0] += red[(rme*2 + 0)*64 + l];
    acc[a][1] += red[(rme*2 + 1)*64 + l];
    __builtin_amdgcn_s_barrier();
  }

  if (MODE == 0){
    #pragma unroll
    for (int a = 0; a < 8; a++){
      #pragma unroll
      for (int jj = 0; jj < 2; jj++){
        int col   = (int)nbase + wn*64 + (wk*2 + jj)*16 + lr;
        int which = col >> 10;
        int h     = (col >> 6) & 15;
        int d     = col & 63;
        int m0    = (int)mbase + wm*128 + a*16 + lg*4;
        int b     = m0 >> 11, ns0 = m0 & 2047;
        int bh    = (b << 4) + h;
        f32x4 v   = (jj == 0) ? acc[a][0] : acc[a][1];
        if (which == 2){
          u16x4 pk;
          #pragma unroll
          for (int r = 0; r < 4; r++) pk[r] = f2b(v[r]);
          *(u16x4*)&vtb[((long)bh*64 + d)*2048 + ns0] = pk;
        } else {
          u16* dst  = (which == 0) ? qb : kb;
          float scl = (which == 0) ? QSCALE : 1.0f;
          #pragma unroll
          for (int r = 0; r < 4; r++)
            dst[((long)bh * 2048 + ns0 + r) * 64 + d] = f2b(v[r] * scl);
        }
      }
    }
  } else {
    #pragma unroll
    for (int a = 0; a < 8; a++){
      #pragma unroll
      for (int jj = 0; jj < 2; jj++){
        int c = (int)nbase + wn*64 + (wk*2 + jj)*16 + lr;
        float bv = bias[c];
        f32x4 v = (jj == 0) ? acc[a][0] : acc[a][1];
        #pragma unroll
        for (int r = 0; r < 4; r++){
          int m = (int)mbase + wm*128 + a*16 + lg*4 + r;
          outF[(long)m * N + c] = v[r] + bv;
        }
      }
    }
  }
}

// ------ flash attention: 4 waves x 64 q-rows (256 q/block), KV-tile 64 -------
// (R9-exact: best verified attn config, 79.6 us)
__global__ __launch_bounds__(256, 2) void attn_fused(
    const u16* __restrict__ qb, const u16* __restrict__ kb,
    const u16* __restrict__ vtb, u16* __restrict__ ob)
{
  __shared__ u16 k_lds[2][64*64];
  __shared__ u16 vt_lds[2][64*64];
  const int t  = threadIdx.x;            // 0..255
  const int l  = t & 63, lr = l & 15, lg = l >> 4;
  const int w  = t >> 6;                 // 0..3
  const int bid = blockIdx.x;
  const int vid = (bid & 7) * 64 + (bid >> 3);      // XCD-contiguous (512 wg)
  const int bh = vid >> 3, qt = vid & 7;
  const int qrow = qt*256 + w*64;
  const int h7 = lr & 7;

  const u16* Qp = qb + ((long)bh*2048 + qrow)*64;
  bf16x8 qf0[4], qf1[4];
  #pragma unroll
  for (int g = 0; g < 4; g++){
    qf0[g] = *(const bf16x8*)&Qp[(g*16+lr)*64 + lg*8];
    qf1[g] = *(const bf16x8*)&Qp[(g*16+lr)*64 + 32 + lg*8];
  }

  const int r1 = t >> 3;
  const int cx = ((t & 7) ^ (r1 & 7)) * 8;
  const u16* Kp = kb  + (long)bh*2048*64;
  const u16* Vt = vtb + (long)bh*64*2048;
  const int koff0 = r1*64 + cx,        koff1 = (r1+32)*64 + cx;
  const int voff0 = r1*2048 + cx,      voff1 = (r1+32)*2048 + cx;

#define STAGE(kv, buf) do { \
    gload_lds16(Kp + (long)(kv)*64 + koff0, &k_lds[buf][t*8]); \
    gload_lds16(Kp + (long)(kv)*64 + koff1, &k_lds[buf][2048 + t*8]); \
    gload_lds16(Vt + (kv) + voff0, &vt_lds[buf][t*8]); \
    gload_lds16(Vt + (kv) + voff1, &vt_lds[buf][2048 + t*8]); \
  } while(0)

  f32x4 z = {0.f,0.f,0.f,0.f};
  f32x4 oacc[4][4];
  f32x2 sacc[4];
  #pragma unroll
  for (int g = 0; g < 4; g++){
    sacc[g] = (f32x2){0.f, 0.f};
    #pragma unroll
    for (int nt = 0; nt < 4; nt++) oacc[g][nt] = z;
  }

  STAGE(0, 0);
  for (int it = 0; it < 32; ++it){
    const int cur = it & 1;
    __syncthreads();                     // buf[cur] ready (barrier drains vmcnt)
    if (it < 31) STAGE((it+1)*64, cur^1);

    const u16* kl = k_lds[cur];
    const u16* vl = vt_lds[cur];

    // S^T: lane holds cols q = g*16+lr, rows k = k4*16 + lg*4 + r
    f32x4 st[4][4];
    __builtin_amdgcn_s_setprio(1);
    #pragma unroll
    for (int k4 = 0; k4 < 4; k4++){
      const int row = (k4*16 + lr)*64;
      bf16x8 kf0 = *(const bf16x8*)&kl[row + ((0+lg)^h7)*8];
      bf16x8 kf1 = *(const bf16x8*)&kl[row + ((4+lg)^h7)*8];
      #pragma unroll
      for (int g = 0; g < 4; g++){
        st[g][k4] = MFMA16(kf0, qf0[g], z);
        st[g][k4] = MFMA16(kf1, qf1[g], st[g][k4]);
      }
    }
    __builtin_amdgcn_s_setprio(0);

    // shift-free: P = 2^s; per-lane partial sums; pack to sigma A-fragments
    bf16x8 pa0[4], pa1[4];
    #pragma unroll
    for (int g = 0; g < 4; g++){
      u32 wv[4][2];
      #pragma unroll
      for (int k4 = 0; k4 < 4; k4++){
        f32x2 e0 = lo2(st[g][k4]), e1 = hi2(st[g][k4]);
        e0[0] = exp2_raw(e0[0]); e0[1] = exp2_raw(e0[1]);
        e1[0] = exp2_raw(e1[0]); e1[1] = exp2_raw(e1[1]);
        sacc[g] += e0 + e1;
        wv[k4][0] = cvt_pk_bf16(e0[0], e0[1]);
        wv[k4][1] = cvt_pk_bf16(e1[0], e1[1]);
      }
      union { u32 u[4]; bf16x8 v; } p0, p1;
      p0.u[0]=wv[0][0]; p0.u[1]=wv[0][1]; p0.u[2]=wv[1][0]; p0.u[3]=wv[1][1];
      p1.u[0]=wv[2][0]; p1.u[1]=wv[2][1]; p1.u[2]=wv[3][0]; p1.u[3]=wv[3][1];
      pa0[g] = p0.v; pa1[g] = p1.v;
    }

    // O += P V : V fragment shared by all 4 groups (8 MFMA per read pair)
    const int vhalf = (lg & 1) * 4;
    const int cA    = lg >> 1;
    #pragma unroll
    for (int nt = 0; nt < 4; nt++){
      const int rb = (nt*16 + lr)*64;
      u16x4 a0_ = *(const u16x4*)&vl[rb + ((cA     ^ h7)*8) + vhalf];
      u16x4 a1_ = *(const u16x4*)&vl[rb + (((cA+2) ^ h7)*8) + vhalf];
      u16x4 a2_ = *(const u16x4*)&vl[rb + (((cA+4) ^ h7)*8) + vhalf];
      u16x4 a3_ = *(const u16x4*)&vl[rb + (((cA+6) ^ h7)*8) + vhalf];
      u16x8 s0 = __builtin_shufflevector(a0_, a1_, 0,1,2,3,4,5,6,7);
      u16x8 s1 = __builtin_shufflevector(a2_, a3_, 0,1,2,3,4,5,6,7);
      __builtin_amdgcn_s_setprio(1);
      #pragma unroll
      for (int g = 0; g < 4; g++){
        oacc[g][nt] = MFMA16(pa0[g], *(bf16x8*)&s0, oacc[g][nt]);
        oacc[g][nt] = MFMA16(pa1[g], *(bf16x8*)&s1, oacc[g][nt]);
      }
      __builtin_amdgcn_s_setprio(0);
    }
  }
#undef STAGE

  const int b = bh >> 4, h = bh & 15;
  #pragma unroll
  for (int g = 0; g < 4; g++){
    float rs = sacc[g][0] + sacc[g][1];
    rs += __shfl_xor(rs, 16, 64);
    rs += __shfl_xor(rs, 32, 64);
    float linv = 1.0f / rs;
    #pragma unroll
    for (int r = 0; r < 4; r++){
      float lrr = __shfl(linv, lg*4 + r, 64);
      long m = (long)b*2048 + qrow + g*16 + lg*4 + r;
      #pragma unroll
      for (int nt = 0; nt < 4; nt++)
        ob[m*1024 + h*64 + nt*16 + lr] = f2b(oacc[g][nt][r] * lrr);
    }
  }
}

extern "C" void kernel_launch(void* const* d_in, const int* in_sizes, int n_in,
                              void* d_out, int out_size, void* d_ws, size_t ws_size,
                              hipStream_t stream)
{
  const float* x      = (const float*)d_in[0];
  const float* w_qkv  = (const float*)d_in[1];
  const float* w_proj = (const float*)d_in[2];
  const float* b_proj = (const float*)d_in[3];
  float* out = (float*)d_out;

  char* ws = (char*)d_ws;
  size_t off = 0;
  u16* xb     = (u16*)(ws + off);                 // 16MB: cast out / gemm1 in
  u16* obuf   = xb;                               // aliases xb (dead after gemm1)
  off += (size_t)8192*1024*2;
  u16* wqkvt  = (u16*)(ws + off); off += (size_t)3072*1024*2;
  u16* wprojt = (u16*)(ws + off); off += (size_t)1024*1024*2;
  u16* qbuf   = (u16*)(ws + off); off += (size_t)64*2048*64*2;
  u16* kbuf   = (u16*)(ws + off); off += (size_t)64*2048*64*2;
  u16* vtb    = (u16*)(ws + off); off += (size_t)64*64*2048*2;

  hipFuncSetAttribute(reinterpret_cast<const void*>(&gemm8<0>),
                      hipFuncAttributeMaxDynamicSharedMemorySize, 147456);
  hipFuncSetAttribute(reinterpret_cast<const void*>(&gemm8<1>),
                      hipFuncAttributeMaxDynamicSharedMemorySize, 147456);

  prep<<<dim3(6144), 256, 0, stream>>>(x, xb, w_qkv, wqkvt, w_proj, wprojt);

  gemm8<0><<<dim3(768), 512, 147456, stream>>>(xb, wqkvt, 8192, 3072, 1024,
                                               nullptr, nullptr, qbuf, kbuf, vtb);
  attn_fused<<<dim3(512), 256, 0, stream>>>(qbuf, kbuf, vtb, obuf);
  gemm8<1><<<dim3(256), 512, 147456, stream>>>(obuf, wprojt, 8192, 1024, 1024,
                                               out, b_proj, nullptr, nullptr, nullptr);
}

// Round 17
// 175.108 us; speedup vs baseline: 1.2276x; 1.0053x over previous
//
#include <hip/hip_runtime.h>

typedef unsigned short u16;
typedef unsigned int   u32;
typedef __attribute__((ext_vector_type(2))) float    f32x2;
typedef __attribute__((ext_vector_type(4))) float    f32x4;
typedef __attribute__((ext_vector_type(8))) __bf16   bf16x8;
typedef __attribute__((ext_vector_type(8))) unsigned short u16x8;
typedef __attribute__((ext_vector_type(4))) unsigned short u16x4;
typedef __attribute__((ext_vector_type(4))) float    float4v;

#define MFMA16(a,b,c) __builtin_amdgcn_mfma_f32_16x16x32_bf16((a),(b),(c),0,0,0)
// softmax scale folded with log2(e): 0.125 * 1.4426950408889634
#define QSCALE 0.18033688011112042f

__device__ __forceinline__ u16 f2b(float f){
  union { float f; unsigned u; } v; v.f = f;
  return (u16)((v.u + 0x7fffu + ((v.u >> 16) & 1u)) >> 16);
}

__device__ __forceinline__ u32 cvt_pk_bf16(float lo, float hi){
  u32 r;
  asm("v_cvt_pk_bf16_f32 %0, %1, %2" : "=v"(r) : "v"(lo), "v"(hi));
  return r;
}

__device__ __forceinline__ float exp2_raw(float x){
  float r;
  asm("v_exp_f32 %0, %1" : "=v"(r) : "v"(x));
  return r;
}

__device__ __forceinline__ f32x2 lo2(f32x4 v){ return __builtin_shufflevector(v, v, 0, 1); }
__device__ __forceinline__ f32x2 hi2(f32x4 v){ return __builtin_shufflevector(v, v, 2, 3); }

__device__ __forceinline__ void gload_lds16(const void* g, void* l){
  __builtin_amdgcn_global_load_lds(
      (const __attribute__((address_space(1))) void*)g,
      (__attribute__((address_space(3))) void*)l, 16, 0, 0);
}

// ---- fused prep: blocks [0,2048) cast x->bf16; [2048,5120) tcast w_qkv;
// ---- [5120,6144) tcast w_proj.  (verified R15)
__global__ __launch_bounds__(256) void prep(
    const float* __restrict__ x,      u16* __restrict__ xb,
    const float* __restrict__ wqkv,   u16* __restrict__ wqkvt,
    const float* __restrict__ wproj,  u16* __restrict__ wprojt)
{
  __shared__ float tile[32][33];
  const int bid = blockIdx.x;
  const int t   = threadIdx.x;

  if (bid < 2048){
    const int n4 = (8192*1024)/4;
    int i = bid * 256 + t;
    const int st = 2048 * 256;
    for (; i < n4; i += st){
      float4v v = ((const float4v*)x)[i];
      u16x4 o;
      o[0] = f2b(v[0]); o[1] = f2b(v[1]); o[2] = f2b(v[2]); o[3] = f2b(v[3]);
      ((u16x4*)xb)[i] = o;
    }
    return;
  }

  const float* src; u16* dst; int R, C, bx, by;
  if (bid < 5120){
    int rel = bid - 2048;
    src = wqkv; dst = wqkvt; R = 1024; C = 3072;
    bx = rel % 96; by = rel / 96;
  } else {
    int rel = bid - 5120;
    src = wproj; dst = wprojt; R = 1024; C = 1024;
    bx = rel % 32; by = rel / 32;
  }
  const int tx = t & 31, ty = t >> 5;
  const int c0 = bx * 32, r0 = by * 32;
  #pragma unroll
  for (int i = 0; i < 4; i++)
    tile[ty + i*8][tx] = src[(long)(r0 + ty + i*8) * C + c0 + tx];
  __syncthreads();
  #pragma unroll
  for (int i = 0; i < 4; i++)
    dst[(long)(c0 + ty + i*8) * R + r0 + tx] = f2b(tile[tx][ty + i*8]);
}

// ====== k-split GEMM: C = A[M,K] @ Bt[N,K]^T, BM=256 BN=128, BK=64 ===========
// (verified R9/R15: 3-slot ring, vmcnt(6)/tile, XOR swizzle, XCD remap)
template<int MODE>
__global__ __launch_bounds__(512, 2) void gemm8(
    const u16* __restrict__ A, const u16* __restrict__ Bt,
    int M, int N, int K,
    float* __restrict__ outF, const float* __restrict__ bias,
    u16* __restrict__ qb, u16* __restrict__ kb, u16* __restrict__ vtb)
{
  extern __shared__ u16 lds[];
  u16* aL = lds;             // 3 slots x 16384 u16 (32KB)
  u16* bL = lds + 49152;     // 3 slots x  8192 u16 (16KB)

  const int t  = threadIdx.x;          // 0..511
  const int l  = t & 63, lr = l & 15, lg = l >> 4;
  const int w  = t >> 6;               // 0..7
  const int wm = w >> 2, wn = (w >> 1) & 1, wk = w & 1;
  const int bid = blockIdx.x;
  const int xcd = bid & 7, idx = bid >> 3;
  const long mbase = (long)(xcd*4 + (idx & 3)) * 256;
  const long nbase = (long)(idx >> 2) * 128;

  const int xr0 = t >> 3;
  const int xc  = t & 7;
  const int xswz = (xc ^ (xr0 & 7)) << 3;

#define STG(F_) do { \
    const int T_ = (F_) >> 2, h_ = (F_) & 3, slot_ = T_ % 3; \
    if ((h_ & 1) == 0){ const int ah = h_ >> 1; \
      const u16* g_ = A + (mbase + ah*128 + xr0)*(long)K + T_*64 + xswz; \
      u16* d_ = aL + slot_*16384 + ah*8192 + t*8; \
      gload_lds16(g_, d_); \
      gload_lds16(g_ + 64*(long)K, d_ + 4096); \
    } else { const int bh_ = h_ >> 1; \
      const u16* g_ = Bt + (nbase + bh_*64 + xr0)*(long)K + T_*64 + xswz; \
      gload_lds16(g_, bL + slot_*8192 + bh_*4096 + t*8); } \
  } while(0)

#define VMCNT(n) asm volatile("s_waitcnt vmcnt(" #n ")" ::: "memory")
#define BAR() __builtin_amdgcn_s_barrier()

  f32x4 z = {0.f,0.f,0.f,0.f};
  f32x4 acc[8][4];
  #pragma unroll
  for (int a = 0; a < 8; a++)
    #pragma unroll
    for (int j = 0; j < 4; j++) acc[a][j] = z;

  const int kc = wk*4;   // k-half chunk base for this wave

  STG(0); STG(1); STG(2); STG(3);
  STG(4); STG(5); STG(6); STG(7);
  VMCNT(6);
  BAR();

  for (int T = 0; T < 16; ++T){
    const int abuf = (T % 3) * 16384;
    const int bbuf = (T % 3) * 8192;
    bf16x8 afi[8], bfj[4];

    #pragma unroll
    for (int j = 0; j < 4; j++){
      const int rb = wn*64 + j*16 + lr;
      bfj[j] = *(const bf16x8*)&bL[bbuf + rb*64 + (((kc+lg)^(rb&7))<<3)];
    }
    #pragma unroll
    for (int i = 0; i < 8; i++){
      const int ra = wm*128 + i*16 + lr;
      afi[i] = *(const bf16x8*)&aL[abuf + ra*64 + (((kc+lg)^(ra&7))<<3)];
    }
    if (T < 14){
      STG(4*(T+2)); STG(4*(T+2)+1); STG(4*(T+2)+2); STG(4*(T+2)+3);
      VMCNT(6);
    } else if (T == 14){
      VMCNT(0);
    }
    BAR();
    __builtin_amdgcn_s_setprio(1);
    #pragma unroll
    for (int i = 0; i < 8; i++)
      #pragma unroll
      for (int j = 0; j < 4; j++)
        acc[i][j] = MFMA16(afi[i], bfj[j], acc[i][j]);
    __builtin_amdgcn_s_setprio(0);
    BAR();
  }
#undef STG
#undef VMCNT
#undef BAR

  if (wk){
    #pragma unroll
    for (int a = 0; a < 8; a++){
      f32x4 t0 = acc[a][0]; acc[a][0] = acc[a][2]; acc[a][2] = t0;
      f32x4 t1 = acc[a][1]; acc[a][1] = acc[a][3]; acc[a][3] = t1;
    }
  }
  f32x4* red = (f32x4*)lds;
  const int pb = (wm*2 + wn)*2;
  const int wme = pb + (1 - wk);
  const int rme = pb + wk;
  #pragma unroll
  for (int a = 0; a < 8; a++){
    red[(wme*2 + 0)*64 + l] = acc[a][2];
    red[(wme*2 + 1)*64 + l] = acc[a][3];
    __builtin_amdgcn_s_barrier();
    acc[a][0] += red[(rme*2 + 0)*64 + l];
    acc[a][1] += red[(rme*2 + 1)*64 + l];
    __builtin_amdgcn_s_barrier();
  }

  if (MODE == 0){
    #pragma unroll
    for (int a = 0; a < 8; a++){
      #pragma unroll
      for (int jj = 0; jj < 2; jj++){
        int col   = (int)nbase + wn*64 + (wk*2 + jj)*16 + lr;
        int which = col >> 10;
        int h     = (col >> 6) & 15;
        int d     = col & 63;
        int m0    = (int)mbase + wm*128 + a*16 + lg*4;
        int b     = m0 >> 11, ns0 = m0 & 2047;
        int bh    = (b << 4) + h;
        f32x4 v   = (jj == 0) ? acc[a][0] : acc[a][1];
        if (which == 2){
          u16x4 pk;
          #pragma unroll
          for (int r = 0; r < 4; r++) pk[r] = f2b(v[r]);
          *(u16x4*)&vtb[((long)bh*64 + d)*2048 + ns0] = pk;
        } else {
          u16* dst  = (which == 0) ? qb : kb;
          float scl = (which == 0) ? QSCALE : 1.0f;
          #pragma unroll
          for (int r = 0; r < 4; r++)
            dst[((long)bh * 2048 + ns0 + r) * 64 + d] = f2b(v[r] * scl);
        }
      }
    }
  } else {
    #pragma unroll
    for (int a = 0; a < 8; a++){
      #pragma unroll
      for (int jj = 0; jj < 2; jj++){
        int c = (int)nbase + wn*64 + (wk*2 + jj)*16 + lr;
        float bv = bias[c];
        f32x4 v = (jj == 0) ? acc[a][0] : acc[a][1];
        #pragma unroll
        for (int r = 0; r < 4; r++){
          int m = (int)mbase + wm*128 + a*16 + lg*4 + r;
          outF[(long)m * N + c] = v[r] + bv;
        }
      }
    }
  }
}

// ------ flash attention: 4 waves x 64 q-rows (256 q/block), KV-tile 64 -------
// (R9-exact: best verified attn config, 79.6 us)
__global__ __launch_bounds__(256, 2) void attn_fused(
    const u16* __restrict__ qb, const u16* __restrict__ kb,
    const u16* __restrict__ vtb, u16* __restrict__ ob)
{
  __shared__ u16 k_lds[2][64*64];
  __shared__ u16 vt_lds[2][64*64];
  const int t  = threadIdx.x;            // 0..255
  const int l  = t & 63, lr = l & 15, lg = l >> 4;
  const int w  = t >> 6;                 // 0..3
  const int bid = blockIdx.x;
  const int vid = (bid & 7) * 64 + (bid >> 3);      // XCD-contiguous (512 wg)
  const int bh = vid >> 3, qt = vid & 7;
  const int qrow = qt*256 + w*64;
  const int h7 = lr & 7;

  const u16* Qp = qb + ((long)bh*2048 + qrow)*64;
  bf16x8 qf0[4], qf1[4];
  #pragma unroll
  for (int g = 0; g < 4; g++){
    qf0[g] = *(const bf16x8*)&Qp[(g*16+lr)*64 + lg*8];
    qf1[g] = *(const bf16x8*)&Qp[(g*16+lr)*64 + 32 + lg*8];
  }

  const int r1 = t >> 3;
  const int cx = ((t & 7) ^ (r1 & 7)) * 8;
  const u16* Kp = kb  + (long)bh*2048*64;
  const u16* Vt = vtb + (long)bh*64*2048;
  const int koff0 = r1*64 + cx,        koff1 = (r1+32)*64 + cx;
  const int voff0 = r1*2048 + cx,      voff1 = (r1+32)*2048 + cx;

#define STAGE(kv, buf) do { \
    gload_lds16(Kp + (long)(kv)*64 + koff0, &k_lds[buf][t*8]); \
    gload_lds16(Kp + (long)(kv)*64 + koff1, &k_lds[buf][2048 + t*8]); \
    gload_lds16(Vt + (kv) + voff0, &vt_lds[buf][t*8]); \
    gload_lds16(Vt + (kv) + voff1, &vt_lds[buf][2048 + t*8]); \
  } while(0)

  f32x4 z = {0.f,0.f,0.f,0.f};
  f32x4 oacc[4][4];
  f32x2 sacc[4];
  #pragma unroll
  for (int g = 0; g < 4; g++){
    sacc[g] = (f32x2){0.f, 0.f};
    #pragma unroll
    for (int nt = 0; nt < 4; nt++) oacc[g][nt] = z;
  }

  STAGE(0, 0);
  for (int it = 0; it < 32; ++it){
    const int cur = it & 1;
    __syncthreads();                     // buf[cur] ready (barrier drains vmcnt)
    if (it < 31) STAGE((it+1)*64, cur^1);

    const u16* kl = k_lds[cur];
    const u16* vl = vt_lds[cur];

    // S^T: lane holds cols q = g*16+lr, rows k = k4*16 + lg*4 + r
    f32x4 st[4][4];
    __builtin_amdgcn_s_setprio(1);
    #pragma unroll
    for (int k4 = 0; k4 < 4; k4++){
      const int row = (k4*16 + lr)*64;
      bf16x8 kf0 = *(const bf16x8*)&kl[row + ((0+lg)^h7)*8];
      bf16x8 kf1 = *(const bf16x8*)&kl[row + ((4+lg)^h7)*8];
      #pragma unroll
      for (int g = 0; g < 4; g++){
        st[g][k4] = MFMA16(kf0, qf0[g], z);
        st[g][k4] = MFMA16(kf1, qf1[g], st[g][k4]);
      }
    }
    __builtin_amdgcn_s_setprio(0);

    // shift-free: P = 2^s; per-lane partial sums; pack to sigma A-fragments
    bf16x8 pa0[4], pa1[4];
    #pragma unroll
    for (int g = 0; g < 4; g++){
      u32 wv[4][2];
      #pragma unroll
      for (int k4 = 0; k4 < 4; k4++){
        f32x2 e0 = lo2(st[g][k4]), e1 = hi2(st[g][k4]);
        e0[0] = exp2_raw(e0[0]); e0[1] = exp2_raw(e0[1]);
        e1[0] = exp2_raw(e1[0]); e1[1] = exp2_raw(e1[1]);
        sacc[g] += e0 + e1;
        wv[k4][0] = cvt_pk_bf16(e0[0], e0[1]);
        wv[k4][1] = cvt_pk_bf16(e1[0], e1[1]);
      }
      union { u32 u[4]; bf16x8 v; } p0, p1;
      p0.u[0]=wv[0][0]; p0.u[1]=wv[0][1]; p0.u[2]=wv[1][0]; p0.u[3]=wv[1][1];
      p1.u[0]=wv[2][0]; p1.u[1]=wv[2][1]; p1.u[2]=wv[3][0]; p1.u[3]=wv[3][1];
      pa0[g] = p0.v; pa1[g] = p1.v;
    }

    // O += P V : V fragment shared by all 4 groups (8 MFMA per read pair)
    const int vhalf = (lg & 1) * 4;
    const int cA    = lg >> 1;
    #pragma unroll
    for (int nt = 0; nt < 4; nt++){
      const int rb = (nt*16 + lr)*64;
      u16x4 a0_ = *(const u16x4*)&vl[rb + ((cA     ^ h7)*8) + vhalf];
      u16x4 a1_ = *(const u16x4*)&vl[rb + (((cA+2) ^ h7)*8) + vhalf];
      u16x4 a2_ = *(const u16x4*)&vl[rb + (((cA+4) ^ h7)*8) + vhalf];
      u16x4 a3_ = *(const u16x4*)&vl[rb + (((cA+6) ^ h7)*8) + vhalf];
      u16x8 s0 = __builtin_shufflevector(a0_, a1_, 0,1,2,3,4,5,6,7);
      u16x8 s1 = __builtin_shufflevector(a2_, a3_, 0,1,2,3,4,5,6,7);
      __builtin_amdgcn_s_setprio(1);
      #pragma unroll
      for (int g = 0; g < 4; g++){
        oacc[g][nt] = MFMA16(pa0[g], *(bf16x8*)&s0, oacc[g][nt]);
        oacc[g][nt] = MFMA16(pa1[g], *(bf16x8*)&s1, oacc[g][nt]);
      }
      __builtin_amdgcn_s_setprio(0);
    }
  }
#undef STAGE

  const int b = bh >> 4, h = bh & 15;
  #pragma unroll
  for (int g = 0; g < 4; g++){
    float rs = sacc[g][0] + sacc[g][1];
    rs += __shfl_xor(rs, 16, 64);
    rs += __shfl_xor(rs, 32, 64);
    float linv = 1.0f / rs;
    #pragma unroll
    for (int r = 0; r < 4; r++){
      float lrr = __shfl(linv, lg*4 + r, 64);
      long m = (long)b*2048 + qrow + g*16 + lg*4 + r;
      #pragma unroll
      for (int nt = 0; nt < 4; nt++)
        ob[m*1024 + h*64 + nt*16 + lr] = f2b(oacc[g][nt][r] * lrr);
    }
  }
}

extern "C" void kernel_launch(void* const* d_in, const int* in_sizes, int n_in,
                              void* d_out, int out_size, void* d_ws, size_t ws_size,
                              hipStream_t stream)
{
  const float* x      = (const float*)d_in[0];
  const float* w_qkv  = (const float*)d_in[1];
  const float* w_proj = (const float*)d_in[2];
  const float* b_proj = (const float*)d_in[3];
  float* out = (float*)d_out;

  char* ws = (char*)d_ws;
  size_t off = 0;
  u16* xb     = (u16*)(ws + off);                 // 16MB: cast out / gemm1 in
  u16* obuf   = xb;                               // aliases xb (dead after gemm1)
  off += (size_t)8192*1024*2;
  u16* wqkvt  = (u16*)(ws + off); off += (size_t)3072*1024*2;
  u16* wprojt = (u16*)(ws + off); off += (size_t)1024*1024*2;
  u16* qbuf   = (u16*)(ws + off); off += (size_t)64*2048*64*2;
  u16* kbuf   = (u16*)(ws + off); off += (size_t)64*2048*64*2;
  u16* vtb    = (u16*)(ws + off); off += (size_t)64*64*2048*2;

  hipFuncSetAttribute(reinterpret_cast<const void*>(&gemm8<0>),
                      hipFuncAttributeMaxDynamicSharedMemorySize, 147456);
  hipFuncSetAttribute(reinterpret_cast<const void*>(&gemm8<1>),
                      hipFuncAttributeMaxDynamicSharedMemorySize, 147456);

  prep<<<dim3(6144), 256, 0, stream>>>(x, xb, w_qkv, wqkvt, w_proj, wprojt);

  gemm8<0><<<dim3(768), 512, 147456, stream>>>(xb, wqkvt, 8192, 3072, 1024,
                                               nullptr, nullptr, qbuf, kbuf, vtb);
  attn_fused<<<dim3(512), 256, 0, stream>>>(qbuf, kbuf, vtb, obuf);
  gemm8<1><<<dim3(256), 512, 147456, stream>>>(obuf, wprojt, 8192, 1024, 1024,
                                               out, b_proj, nullptr, nullptr, nullptr);
}